// Round 2
// baseline (898.830 us; speedup 1.0000x reference)
//
#include <hip/hip_runtime.h>
#include <hip/hip_bf16.h>
#include <cstdint>
#include <cstddef>

#define DEV __device__ __forceinline__

// problem constants
// B=128, S=512, V=30000, DS=64, DF=300, H=600, BB=2*B=256 combined rows

DEV float geluf(float x){ return 0.5f*x*(1.f + erff(x*0.7071067811865475f)); }

DEV float blk_sum512(float* red, int t, float v){
  red[t] = v; __syncthreads();
  for (int o = 256; o > 0; o >>= 1){ if (t < o) red[t] += red[t+o]; __syncthreads(); }
  float r = red[0]; __syncthreads(); return r;
}
DEV float blk_max512(float* red, int t, float v){
  red[t] = v; __syncthreads();
  for (int o = 256; o > 0; o >>= 1){ if (t < o) red[t] = fmaxf(red[t], red[t+o]); __syncthreads(); }
  float r = red[0]; __syncthreads(); return r;
}

DEV void u_store(float* p, float v){ *p = v; }
DEV void u_store(__hip_bfloat16* p, float v){ *p = __float2bfloat16(v); }
DEV float u_load(const float* p){ return *p; }
DEV float u_load(const __hip_bfloat16* p){ return __bfloat162float(*p); }

// ---- mask dtype is ambiguous across harness versions (bool may arrive as
// u8 / int32 / bf16). Classify from the buffer's own bytes (deterministic).
DEV int mask_mode(const unsigned char* m){
  bool big = false, off123 = false, off0one = false;
  #pragma unroll
  for (int i = 0; i < 16; ++i){
    unsigned char c = m[i];
    if (c > 1) big = true;
    if ((i & 3) != 0 && c != 0) off123 = true;
    if ((i & 3) == 0 && c == 1) off0one = true;
  }
  if (big) return 2;                 // 0x80/0x3F bytes -> bf16-encoded bools
  if (!off123 && off0one) return 1;  // 01 00 00 00 pattern -> int32
  return 0;                          // bytes in {0,1} -> u8
}
DEV float mask_read(const void* m, int idx, int mode){
  if (mode == 1) return ((const int*)m)[idx] ? 1.f : 0.f;
  if (mode == 2) return ((const unsigned short*)m)[idx] ? 1.f : 0.f;
  return ((const unsigned char*)m)[idx] ? 1.f : 0.f;
}

// ---------------- P0a: per-vocab feature stats (sum, sumsq) ----------------
__global__ __launch_bounds__(256)
void k_feat_stats(const float* __restrict__ feat, float* __restrict__ fsum, float* __restrict__ fsq){
  int v = blockIdx.x*4 + (threadIdx.x >> 6);
  int lane = threadIdx.x & 63;
  if (v >= 30000) return;
  float s = 0.f, q = 0.f;
  for (int i = lane; i < 300; i += 64){ float f = feat[v*300 + i]; s += f; q += f*f; }
  for (int o = 32; o > 0; o >>= 1){ s += __shfl_xor(s, o); q += __shfl_xor(q, o); }
  if (lane == 0){ fsum[v] = s; fsq[v] = q; }
}

// ---------------- P0b: partial gw1[j]=sum_i g[i]*w1[i,j], cv[j]=sum_i bln[i]*w1[i,j] ----------------
__global__ __launch_bounds__(256)
void k_gw1_part(const float* __restrict__ w1, const float* __restrict__ g,
                const float* __restrict__ bln, float* __restrict__ pgw, float* __restrict__ pcv){
  int j = blockIdx.x*256 + threadIdx.x;
  int ic = blockIdx.y;              // 8 chunks of 75 rows
  if (j >= 600) return;
  float a = 0.f, c = 0.f;
  for (int i = ic*75; i < ic*75 + 75; ++i){
    float w = w1[i*600 + j];
    a += g[i]*w; c += bln[i]*w;
  }
  pgw[ic*600 + j] = a; pcv[ic*600 + j] = c;
}

// ---------------- P1: U[v,j] = sum_{i<300} feat[v,i]*g[i]*w1[i,j]  (M=30000,K=300,N=600) ----------------
template <typename UT>
__global__ __launch_bounds__(256)
void k_ugemm(const float* __restrict__ feat, const float* __restrict__ w1,
             const float* __restrict__ g, UT* __restrict__ U){
  __shared__ float As[32][65];  // [kk][m]
  __shared__ float Bs[32][65];  // [kk][n]
  int tid = threadIdx.x;
  int tx = tid & 15, ty = tid >> 4;
  int bm = blockIdx.x * 64, bn = blockIdx.y * 64;
  float acc[4][4] = {};
  for (int k0 = 0; k0 < 300; k0 += 32){
    for (int idx = tid; idx < 64*32; idx += 256){
      int m = idx >> 5, kk = idx & 31;
      int row = bm + m, k = k0 + kk;
      As[kk][m] = (row < 30000 && k < 300) ? feat[row*300 + k] : 0.f;
    }
    for (int idx = tid; idx < 32*64; idx += 256){
      int kk = idx >> 6, n = idx & 63;
      int k = k0 + kk, col = bn + n;
      Bs[kk][n] = (k < 300 && col < 600) ? g[k]*w1[k*600 + col] : 0.f;
    }
    __syncthreads();
    #pragma unroll
    for (int kk = 0; kk < 32; ++kk){
      float a[4], b[4];
      #pragma unroll
      for (int i = 0; i < 4; ++i) a[i] = As[kk][ty*4+i];
      #pragma unroll
      for (int j = 0; j < 4; ++j) b[j] = Bs[kk][tx*4+j];
      #pragma unroll
      for (int i = 0; i < 4; ++i)
        #pragma unroll
        for (int j = 0; j < 4; ++j) acc[i][j] += a[i]*b[j];
    }
    __syncthreads();
  }
  for (int i = 0; i < 4; ++i){
    int row = bm + ty*4 + i; if (row >= 30000) continue;
    for (int j = 0; j < 4; ++j){
      int col = bn + tx*4 + j; if (col >= 600) continue;
      u_store(U + (size_t)row*600 + col, acc[i][j]);
    }
  }
}

// ---------------- K1: per-bb stage 1: centroid, kernel, sgs, V, softmax weights, Fbar ----------------
__global__ __launch_bounds__(512)
void k_encode_stage1(const int* __restrict__ ids_a, const void* __restrict__ mask_a,
                     const int* __restrict__ ids_b, const void* __restrict__ mask_b,
                     const float* __restrict__ mu_tab, const float* __restrict__ logvar_tab,
                     const float* __restrict__ alpha_tab, const float* __restrict__ feat_tab,
                     const float* __restrict__ log_tau, const float* __restrict__ pos_mu,
                     const float* __restrict__ pos_alpha,
                     const float* __restrict__ wq, const float* __restrict__ bq,
                     const float* __restrict__ wk, const float* __restrict__ bk,
                     const float* __restrict__ ln1g, const float* __restrict__ w1,
                     float* __restrict__ sgs_g, float* __restrict__ ssum_g, float* __restrict__ ssq_g,
                     float* __restrict__ V_g, float* __restrict__ wgt_g, float* __restrict__ Fbar_g)
{
  int bb = blockIdx.x;
  const int* ids = (bb < 128) ? ids_a : ids_b;
  const void* msk = (bb < 128) ? mask_a : mask_b;
  int b = bb & 127;
  int t = threadIdx.x;

  __shared__ int   ids_l[512];
  __shared__ float mf_l[512], al_l[512], w_l[512], red[512];
  __shared__ float cent[64], q_l[64], qk_l[64];
  __shared__ float sgs_l[300];
  __shared__ float bkq_s;
  __shared__ int mmode;

  if (t == 0) mmode = mask_mode((const unsigned char*)msk);
  __syncthreads();

  // phase 0: load ids/mask, alpha
  {
    int id = ids[b*512 + t];
    float mf = mask_read(msk, b*512 + t, mmode);
    ids_l[t] = id; mf_l[t] = mf;
    float pa = pos_alpha[t];
    al_l[t] = alpha_tab[id] * (1.f/(1.f + expf(-pa))) * mf;
  }
  __syncthreads();
  float msum = blk_sum512(red, t, mf_l[t]);

  // phase 1: centroid
  {
    int d = t & 63, g = t >> 6;
    float p = 0.f;
    for (int k = 0; k < 64; ++k){
      int s = g*64 + k;
      float m = mu_tab[ids_l[s]*64 + d] + pos_mu[s*64 + d];
      p += m * mf_l[s];
    }
    red[g*64 + d] = p;
  }
  __syncthreads();
  if (t < 64){
    float c = 0.f;
    for (int g = 0; g < 8; ++g) c += red[g*64 + t];
    cent[t] = c / fmaxf(msum, 1.f);
  }
  __syncthreads();

  // phase 2: d2 -> w = alpha*K
  {
    int d = t & 63, g = t >> 6;
    float itau = expf(-log_tau[0]);      // 1/tau
    for (int k = 0; k < 64; ++k){
      int s = g*64 + k;
      int id = ids_l[s];
      float m = mu_tab[id*64 + d] + pos_mu[s*64 + d];
      float dv = m - cent[d];
      float val = dv*dv*expf(-logvar_tab[id*64 + d]);
      for (int o = 32; o > 0; o >>= 1) val += __shfl_xor(val, o);
      if (d == 0){
        float K = expf(-0.5f * val * itau) * mf_l[s];
        w_l[s] = al_l[s] * K;
      }
    }
  }
  __syncthreads();
  float wsum = blk_sum512(red, t, w_l[t]);

  // phase 3: sgs render
  if (t < 300){
    float acc = 0.f;
    #pragma unroll 4
    for (int s = 0; s < 512; ++s) acc += w_l[s] * feat_tab[(size_t)ids_l[s]*300 + t];
    float sv = acc / fmaxf(wsum, 1e-8f);
    sgs_l[t] = sv;
    sgs_g[bb*300 + t] = sv;
  }
  __syncthreads();
  float ssum = blk_sum512(red, t, (t < 300) ? sgs_l[t] : 0.f);
  float ssq  = blk_sum512(red, t, (t < 300) ? sgs_l[t]*sgs_l[t] : 0.f);
  if (t == 0){ ssum_g[bb] = ssum; ssq_g[bb] = ssq; }

  // phase 4: query = sgs@wq + bq
  if (t < 64){
    float q = bq[t];
    for (int i = 0; i < 300; ++i) q += sgs_l[i]*wq[i*64 + t];
    q_l[t] = q;
  }
  __syncthreads();
  // qk[d] = sum_j wk[d,j]*q[j];  bkq = bk.q
  if (t < 64){
    float a = 0.f;
    for (int j = 0; j < 64; ++j) a += wk[t*64 + j]*q_l[j];
    qk_l[t] = a;
  }
  if (t == 0){
    float s = 0.f;
    for (int j = 0; j < 64; ++j) s += bk[j]*q_l[j];
    bkq_s = s;
  }
  __syncthreads();

  // phase 5: scores
  {
    int d = t & 63, g = t >> 6;
    for (int k = 0; k < 64; ++k){
      int s = g*64 + k;
      int id = ids_l[s];
      float m = mu_tab[id*64 + d] + pos_mu[s*64 + d];
      float val = m * qk_l[d];
      for (int o = 32; o > 0; o >>= 1) val += __shfl_xor(val, o);
      if (d == 0){
        float sv = (val + bkq_s) * 0.125f;   // /sqrt(64)
        w_l[s] = (mf_l[s] != 0.f) ? sv : -1e30f;
      }
    }
  }
  __syncthreads();

  // phase 6: softmax over 512 scores
  float mx = blk_max512(red, t, w_l[t]);
  float ex = expf(w_l[t] - mx);
  float Z  = blk_sum512(red, t, ex);
  float wgt = ex / Z;
  __syncthreads();
  w_l[t] = wgt;
  wgt_g[bb*512 + t] = wgt;
  __syncthreads();

  // phase 7: Fbar = sum_s weights[s]*feat[id_s]
  if (t < 300){
    float acc = 0.f;
    #pragma unroll 4
    for (int s = 0; s < 512; ++s) acc += w_l[s] * feat_tab[(size_t)ids_l[s]*300 + t];
    Fbar_g[bb*300 + t] = acc;
  }
  // phase 8: V[j] = sum_{i<300} sgs[i]*g[300+i]*w1[300+i, j]
  for (int j = t; j < 600; j += 512){
    float acc = 0.f;
    for (int i = 0; i < 300; ++i) acc += sgs_l[i]*ln1g[300 + i]*w1[(300 + i)*600 + j];
    V_g[bb*600 + j] = acc;
  }
}

// ---------------- K2: hbar[bb,j] = sum_s wgt[s]*gelu((U[id_s,j]+V[j]-m_s*gw1[j])*rs_s + c[j]) ----------------
template <typename UT>
__global__ __launch_bounds__(640)
void k_hbar(const int* __restrict__ ids_a, const int* __restrict__ ids_b,
            const UT* __restrict__ U, const float* __restrict__ fsum, const float* __restrict__ fsq,
            const float* __restrict__ ssum_g, const float* __restrict__ ssq_g,
            const float* __restrict__ V_g, const float* __restrict__ pgw, const float* __restrict__ pcv,
            const float* __restrict__ bias1, const float* __restrict__ wgt_g,
            float* __restrict__ hbar_g)
{
  int bb = blockIdx.x; int b = bb & 127;
  const int* ids = (bb < 128) ? ids_a : ids_b;
  int t = threadIdx.x;
  __shared__ int id_l[512];
  __shared__ float m_l[512], rs_l[512], wg_l[512];
  float ss = ssum_g[bb], sq = ssq_g[bb];
  if (t < 512){
    int id = ids[b*512 + t];
    id_l[t] = id;
    float m = (fsum[id] + ss) * (1.f/600.f);
    float var = (fsq[id] + sq) * (1.f/600.f) - m*m;
    m_l[t] = m;
    rs_l[t] = 1.f / sqrtf(var + 1e-5f);
    wg_l[t] = wgt_g[bb*512 + t];
  }
  __syncthreads();
  if (t < 600){
    float gwj = 0.f, cj = 0.f;
    for (int k = 0; k < 8; ++k){ gwj += pgw[k*600 + t]; cj += pcv[k*600 + t]; }
    cj += bias1[t];
    float Vj = V_g[bb*600 + t];
    float acc = 0.f;
    #pragma unroll 4
    for (int s = 0; s < 512; ++s){
      float u = u_load(U + (size_t)id_l[s]*600 + t);
      float a = (u + Vj - m_l[s]*gwj)*rs_l[s] + cj;
      acc += wg_l[s] * geluf(a);
    }
    hbar_g[bb*600 + t] = acc;
  }
}

// ---------------- K3: attn = Fbar + hbar@w2 + b2; final = sgs + MLP2([sgs, attn]) ----------------
__global__ __launch_bounds__(512)
void k_final(const float* __restrict__ hbar_g, const float* __restrict__ Fbar_g,
             const float* __restrict__ sgs_g,
             const float* __restrict__ w2, const float* __restrict__ b2,
             const float* __restrict__ ln2g, const float* __restrict__ ln2b,
             const float* __restrict__ aw1, const float* __restrict__ ab1,
             const float* __restrict__ aw2, const float* __restrict__ ab2,
             float* __restrict__ final_g)
{
  int bb = blockIdx.x, t = threadIdx.x;
  __shared__ float hb[600], att[300], sg[300], t2[600], g2[600], red[512];
  for (int j = t; j < 600; j += 512) hb[j] = hbar_g[bb*600 + j];
  if (t < 300) sg[t] = sgs_g[bb*300 + t];
  __syncthreads();
  if (t < 300){
    float acc = b2[t] + Fbar_g[bb*300 + t];
    for (int k = 0; k < 600; ++k) acc += hb[k]*w2[k*300 + t];
    att[t] = acc;
  }
  __syncthreads();
  float S1 = blk_sum512(red, t, (t < 300) ? (sg[t] + att[t]) : 0.f);
  float S2 = blk_sum512(red, t, (t < 300) ? (sg[t]*sg[t] + att[t]*att[t]) : 0.f);
  float m = S1*(1.f/600.f);
  float var = S2*(1.f/600.f) - m*m;
  float rs = 1.f / sqrtf(var + 1e-5f);
  for (int i = t; i < 600; i += 512){
    float x = (i < 300) ? sg[i] : att[i - 300];
    t2[i] = (x - m)*rs*ln2g[i] + ln2b[i];
  }
  __syncthreads();
  for (int j = t; j < 600; j += 512){
    float u = ab1[j];
    for (int i = 0; i < 600; ++i) u += t2[i]*aw1[i*600 + j];
    g2[j] = geluf(u);
  }
  __syncthreads();
  if (t < 300){
    float o = sg[t] + ab2[t];
    for (int i = 0; i < 600; ++i) o += g2[i]*aw2[i*300 + t];
    final_g[bb*300 + t] = o;
  }
}

// ---------------- K4: cosine ----------------
__global__ __launch_bounds__(64)
void k_cos(const float* __restrict__ final_g, float* __restrict__ out){
  int b = blockIdx.x; int lane = threadIdx.x;
  const float* A  = final_g + b*300;
  const float* Bv = final_g + (128 + b)*300;
  float dot = 0.f, na = 0.f, nb = 0.f;
  for (int i = lane; i < 300; i += 64){
    float x = A[i], y = Bv[i];
    dot += x*y; na += x*x; nb += y*y;
  }
  for (int o = 32; o > 0; o >>= 1){
    dot += __shfl_xor(dot, o); na += __shfl_xor(na, o); nb += __shfl_xor(nb, o);
  }
  if (lane == 0){
    float den = fmaxf(sqrtf(na), 1e-8f) * fmaxf(sqrtf(nb), 1e-8f);
    out[b] = 5.f * dot / den;
  }
}

extern "C" void kernel_launch(void* const* d_in, const int* in_sizes, int n_in,
                              void* d_out, int out_size, void* d_ws, size_t ws_size,
                              hipStream_t stream) {
  const int* ids_a = (const int*)d_in[0];
  const void* mask_a = d_in[1];
  const int* ids_b = (const int*)d_in[2];
  const void* mask_b = d_in[3];
  const float* mu_tab     = (const float*)d_in[4];
  const float* logvar_tab = (const float*)d_in[5];
  const float* alpha_tab  = (const float*)d_in[6];
  const float* feat_tab   = (const float*)d_in[7];
  const float* log_tau    = (const float*)d_in[8];
  const float* pos_mu     = (const float*)d_in[9];
  const float* pos_alpha  = (const float*)d_in[10];
  const float* ln1g = (const float*)d_in[11];
  const float* ln1b = (const float*)d_in[12];
  const float* w1   = (const float*)d_in[13];
  const float* b1   = (const float*)d_in[14];
  const float* w2   = (const float*)d_in[15];
  const float* b2   = (const float*)d_in[16];
  const float* wq   = (const float*)d_in[17];
  const float* bq   = (const float*)d_in[18];
  const float* wk   = (const float*)d_in[19];
  const float* bk   = (const float*)d_in[20];
  const float* ln2g = (const float*)d_in[21];
  const float* ln2b = (const float*)d_in[22];
  const float* aw1  = (const float*)d_in[23];
  const float* ab1  = (const float*)d_in[24];
  const float* aw2  = (const float*)d_in[25];
  const float* ab2  = (const float*)d_in[26];
  float* out = (float*)d_out;

  char* wsb = (char*)d_ws;
  size_t off = 0;
  auto take = [&](size_t bytes) -> void* {
    void* p = wsb + off;
    off += (bytes + 255) & ~(size_t)255;
    return p;
  };

  const size_t uElems = (size_t)30000 * 600;
  const size_t smallBytes = (size_t)8 << 20;  // generous bound for the small buffers
  bool f32u  = ws_size >= uElems*4 + smallBytes;
  bool bf16u = !f32u && ws_size >= uElems*2 + smallBytes;
  if (!f32u && !bf16u) return;  // cannot run -- fail loudly (output stays poisoned)

  void* U = take(f32u ? uElems*4 : uElems*2);
  float* fsum   = (float*)take(30000*4);
  float* fsq    = (float*)take(30000*4);
  float* pgw    = (float*)take(8*600*4);
  float* pcv    = (float*)take(8*600*4);
  float* sgs_g  = (float*)take(256*300*4);
  float* ssum_g = (float*)take(256*4);
  float* ssq_g  = (float*)take(256*4);
  float* V_g    = (float*)take(256*600*4);
  float* wgt_g  = (float*)take(256*512*4);
  float* Fbar_g = (float*)take(256*300*4);
  float* hbar_g = (float*)take(256*600*4);
  float* final_g= (float*)take(256*300*4);

  k_feat_stats<<<7500, 256, 0, stream>>>(feat_tab, fsum, fsq);
  k_gw1_part<<<dim3(3, 8), 256, 0, stream>>>(w1, ln1g, ln1b, pgw, pcv);
  if (f32u){
    k_ugemm<float><<<dim3(469, 10), 256, 0, stream>>>(feat_tab, w1, ln1g, (float*)U);
  } else {
    k_ugemm<__hip_bfloat16><<<dim3(469, 10), 256, 0, stream>>>(feat_tab, w1, ln1g, (__hip_bfloat16*)U);
  }
  k_encode_stage1<<<256, 512, 0, stream>>>(ids_a, mask_a, ids_b, mask_b,
                                           mu_tab, logvar_tab, alpha_tab, feat_tab,
                                           log_tau, pos_mu, pos_alpha,
                                           wq, bq, wk, bk, ln1g, w1,
                                           sgs_g, ssum_g, ssq_g, V_g, wgt_g, Fbar_g);
  if (f32u){
    k_hbar<float><<<256, 640, 0, stream>>>(ids_a, ids_b, (const float*)U, fsum, fsq,
                                           ssum_g, ssq_g, V_g, pgw, pcv, b1, wgt_g, hbar_g);
  } else {
    k_hbar<__hip_bfloat16><<<256, 640, 0, stream>>>(ids_a, ids_b, (const __hip_bfloat16*)U, fsum, fsq,
                                                    ssum_g, ssq_g, V_g, pgw, pcv, b1, wgt_g, hbar_g);
  }
  k_final<<<256, 512, 0, stream>>>(hbar_g, Fbar_g, sgs_g, w2, b2,
                                   ln2g, ln2b, aw1, ab1, aw2, ab2, final_g);
  k_cos<<<128, 64, 0, stream>>>(final_g, out);
}

// Round 3
// 575.213 us; speedup vs baseline: 1.5626x; 1.5626x over previous
//
#include <hip/hip_runtime.h>
#include <hip/hip_bf16.h>
#include <cstdint>
#include <cstddef>

#define DEV __device__ __forceinline__

// problem constants: B=128, S=512, V=30000, DS=64, DF=300, H=600, BB=256

typedef __attribute__((ext_vector_type(8))) short bf16x8;
typedef __attribute__((ext_vector_type(4))) float f32x4;

DEV float geluf(float x){ return 0.5f*x*(1.f + erff(x*0.7071067811865475f)); }

DEV float blk_sum512(float* red, int t, float v){
  red[t] = v; __syncthreads();
  for (int o = 256; o > 0; o >>= 1){ if (t < o) red[t] += red[t+o]; __syncthreads(); }
  float r = red[0]; __syncthreads(); return r;
}
DEV float blk_max512(float* red, int t, float v){
  red[t] = v; __syncthreads();
  for (int o = 256; o > 0; o >>= 1){ if (t < o) red[t] = fmaxf(red[t], red[t+o]); __syncthreads(); }
  float r = red[0]; __syncthreads(); return r;
}

DEV ushort f2bf(float v){ __hip_bfloat16 h = __float2bfloat16(v); return *(ushort*)&h; }
DEV float bf2f(ushort u){ __hip_bfloat16 h; *(ushort*)&h = u; return __bfloat162float(h); }

// ---- mask dtype classifier (bool may arrive as u8 / int32 / bf16) ----
DEV int mask_mode(const unsigned char* m){
  bool big = false, off123 = false, off0one = false;
  #pragma unroll
  for (int i = 0; i < 16; ++i){
    unsigned char c = m[i];
    if (c > 1) big = true;
    if ((i & 3) != 0 && c != 0) off123 = true;
    if ((i & 3) == 0 && c == 1) off0one = true;
  }
  if (big) return 2;
  if (!off123 && off0one) return 1;
  return 0;
}
DEV float mask_read(const void* m, int idx, int mode){
  if (mode == 1) return ((const int*)m)[idx] ? 1.f : 0.f;
  if (mode == 2) return ((const unsigned short*)m)[idx] ? 1.f : 0.f;
  return ((const unsigned char*)m)[idx] ? 1.f : 0.f;
}

// ---------------- P0a: per-vocab feature stats ----------------
__global__ __launch_bounds__(256)
void k_feat_stats(const float* __restrict__ feat, float* __restrict__ fsum, float* __restrict__ fsq){
  int v = blockIdx.x*4 + (threadIdx.x >> 6);
  int lane = threadIdx.x & 63;
  if (v >= 30000) return;
  float s = 0.f, q = 0.f;
  for (int i = lane; i < 300; i += 64){ float f = feat[v*300 + i]; s += f; q += f*f; }
  for (int o = 32; o > 0; o >>= 1){ s += __shfl_xor(s, o); q += __shfl_xor(q, o); }
  if (lane == 0){ fsum[v] = s; fsq[v] = q; }
}

// ---------------- P0b: gw1/cv partials ----------------
__global__ __launch_bounds__(256)
void k_gw1_part(const float* __restrict__ w1, const float* __restrict__ g,
                const float* __restrict__ bln, float* __restrict__ pgw, float* __restrict__ pcv){
  int j = blockIdx.x*256 + threadIdx.x;
  int ic = blockIdx.y;
  if (j >= 600) return;
  float a = 0.f, c = 0.f;
  for (int i = ic*75; i < ic*75 + 75; ++i){
    float w = w1[i*600 + j];
    a += g[i]*w; c += bln[i]*w;
  }
  pgw[ic*600 + j] = a; pcv[ic*600 + j] = c;
}

// ---------------- pack A: feat -> bf16 [30080][320] (K zero-padded) ----------------
__global__ __launch_bounds__(256)
void k_pack_a(const float* __restrict__ feat, ushort* __restrict__ A){
  int idx = blockIdx.x*256 + threadIdx.x;          // octet index
  if (idx >= 30080*40) return;
  int v = idx / 40, ko = (idx % 40)*8;
  union { ushort u[8]; bf16x8 v8; } pk;
  #pragma unroll
  for (int i = 0; i < 8; ++i){
    int k = ko + i;
    float val = (v < 30000 && k < 300) ? feat[(size_t)v*300 + k] : 0.f;
    pk.u[i] = f2bf(val);
  }
  *(bf16x8*)&A[(size_t)idx*8] = pk.v8;
}

// ---------------- pack B^T: BT[n][k] = g[k]*w1[k*600+n], bf16 [640][320] ----------------
__global__ __launch_bounds__(256)
void k_pack_b(const float* __restrict__ w1, const float* __restrict__ g, ushort* __restrict__ BT){
  int id = blockIdx.x*256 + threadIdx.x;           // 640*320
  if (id >= 640*320) return;
  int n = id % 640, k = id / 640;
  float val = (k < 300 && n < 600) ? g[k]*w1[k*600 + n] : 0.f;
  BT[(size_t)n*320 + k] = f2bf(val);
}

// ---------------- P1: U = A @ B  via MFMA 16x16x32 bf16, 128x128 tile ----------------
__global__ __launch_bounds__(256)
void k_ugemm_mfma(const ushort* __restrict__ A, const ushort* __restrict__ BT,
                  __hip_bfloat16* __restrict__ U){
  __shared__ ushort As[128][40];   // +8 pad: bank-friendly (2-way max)
  __shared__ ushort Bs[128][40];
  int tid = threadIdx.x;
  int bm = blockIdx.x * 128, bn = blockIdx.y * 128;
  int wid = tid >> 6, lane = tid & 63;
  int wr = wid >> 1, wc = wid & 1;
  int lr = lane & 15, lk = lane >> 4;       // frag row/col, k-octet
  f32x4 acc[4][4] = {};
  for (int k0 = 0; k0 < 320; k0 += 32){
    #pragma unroll
    for (int j = 0; j < 2; ++j){
      int idx = tid + 256*j;                // 512 chunks = 128 rows x 4 octets
      int row = idx >> 2, ko = (idx & 3)*8;
      *(bf16x8*)&As[row][ko] = *(const bf16x8*)&A[(size_t)(bm+row)*320 + k0 + ko];
      *(bf16x8*)&Bs[row][ko] = *(const bf16x8*)&BT[(size_t)(bn+row)*320 + k0 + ko];
    }
    __syncthreads();
    bf16x8 af[4], bfr[4];
    #pragma unroll
    for (int f = 0; f < 4; ++f){
      af[f]  = *(const bf16x8*)&As[wr*64 + f*16 + lr][lk*8];
      bfr[f] = *(const bf16x8*)&Bs[wc*64 + f*16 + lr][lk*8];
    }
    #pragma unroll
    for (int i = 0; i < 4; ++i)
      #pragma unroll
      for (int j = 0; j < 4; ++j)
        acc[i][j] = __builtin_amdgcn_mfma_f32_16x16x32_bf16(af[i], bfr[j], acc[i][j], 0, 0, 0);
    __syncthreads();
  }
  #pragma unroll
  for (int i = 0; i < 4; ++i){
    #pragma unroll
    for (int j = 0; j < 4; ++j){
      #pragma unroll
      for (int r = 0; r < 4; ++r){
        int row = bm + wr*64 + i*16 + lk*4 + r;   // C/D: row=(lane>>4)*4+reg
        int col = bn + wc*64 + j*16 + lr;         //      col=lane&15
        if (row < 30000 && col < 600)
          U[(size_t)row*600 + col] = __float2bfloat16(acc[i][j][r]);
      }
    }
  }
}

// ---------------- K1: per-bb stage 1 ----------------
__global__ __launch_bounds__(512)
void k_encode_stage1(const int* __restrict__ ids_a, const void* __restrict__ mask_a,
                     const int* __restrict__ ids_b, const void* __restrict__ mask_b,
                     const float* __restrict__ mu_tab, const float* __restrict__ logvar_tab,
                     const float* __restrict__ alpha_tab, const float* __restrict__ feat_tab,
                     const float* __restrict__ log_tau, const float* __restrict__ pos_mu,
                     const float* __restrict__ pos_alpha,
                     const float* __restrict__ wq, const float* __restrict__ bq,
                     const float* __restrict__ wk, const float* __restrict__ bk,
                     const float* __restrict__ ln1g, const float* __restrict__ w1,
                     float* __restrict__ sgs_g, float* __restrict__ ssum_g, float* __restrict__ ssq_g,
                     float* __restrict__ V_g, float* __restrict__ wgt_g, float* __restrict__ Fbar_g)
{
  int bb = blockIdx.x;
  const int* ids = (bb < 128) ? ids_a : ids_b;
  const void* msk = (bb < 128) ? mask_a : mask_b;
  int b = bb & 127;
  int t = threadIdx.x;

  __shared__ int   ids_l[512];
  __shared__ float mf_l[512], al_l[512], w_l[512], red[512];
  __shared__ float cent[64], q_l[64], qk_l[64];
  __shared__ float sgs_l[300];
  __shared__ float bkq_s;
  __shared__ int mmode;

  if (t == 0) mmode = mask_mode((const unsigned char*)msk);
  __syncthreads();

  {
    int id = ids[b*512 + t];
    float mf = mask_read(msk, b*512 + t, mmode);
    ids_l[t] = id; mf_l[t] = mf;
    float pa = pos_alpha[t];
    al_l[t] = alpha_tab[id] * (1.f/(1.f + expf(-pa))) * mf;
  }
  __syncthreads();
  float msum = blk_sum512(red, t, mf_l[t]);

  {
    int d = t & 63, g = t >> 6;
    float p = 0.f;
    for (int k = 0; k < 64; ++k){
      int s = g*64 + k;
      float m = mu_tab[ids_l[s]*64 + d] + pos_mu[s*64 + d];
      p += m * mf_l[s];
    }
    red[g*64 + d] = p;
  }
  __syncthreads();
  if (t < 64){
    float c = 0.f;
    for (int g = 0; g < 8; ++g) c += red[g*64 + t];
    cent[t] = c / fmaxf(msum, 1.f);
  }
  __syncthreads();

  {
    int d = t & 63, g = t >> 6;
    float itau = expf(-log_tau[0]);
    for (int k = 0; k < 64; ++k){
      int s = g*64 + k;
      int id = ids_l[s];
      float m = mu_tab[id*64 + d] + pos_mu[s*64 + d];
      float dv = m - cent[d];
      float val = dv*dv*expf(-logvar_tab[id*64 + d]);
      for (int o = 32; o > 0; o >>= 1) val += __shfl_xor(val, o);
      if (d == 0){
        float K = expf(-0.5f * val * itau) * mf_l[s];
        w_l[s] = al_l[s] * K;
      }
    }
  }
  __syncthreads();
  float wsum = blk_sum512(red, t, w_l[t]);

  if (t < 300){
    float acc = 0.f;
    #pragma unroll 4
    for (int s = 0; s < 512; ++s) acc += w_l[s] * feat_tab[(size_t)ids_l[s]*300 + t];
    float sv = acc / fmaxf(wsum, 1e-8f);
    sgs_l[t] = sv;
    sgs_g[bb*300 + t] = sv;
  }
  __syncthreads();
  float ssum = blk_sum512(red, t, (t < 300) ? sgs_l[t] : 0.f);
  float ssq  = blk_sum512(red, t, (t < 300) ? sgs_l[t]*sgs_l[t] : 0.f);
  if (t == 0){ ssum_g[bb] = ssum; ssq_g[bb] = ssq; }

  if (t < 64){
    float q = bq[t];
    for (int i = 0; i < 300; ++i) q += sgs_l[i]*wq[i*64 + t];
    q_l[t] = q;
  }
  __syncthreads();
  if (t < 64){
    float a = 0.f;
    for (int j = 0; j < 64; ++j) a += wk[t*64 + j]*q_l[j];
    qk_l[t] = a;
  }
  if (t == 0){
    float s = 0.f;
    for (int j = 0; j < 64; ++j) s += bk[j]*q_l[j];
    bkq_s = s;
  }
  __syncthreads();

  {
    int d = t & 63, g = t >> 6;
    for (int k = 0; k < 64; ++k){
      int s = g*64 + k;
      int id = ids_l[s];
      float m = mu_tab[id*64 + d] + pos_mu[s*64 + d];
      float val = m * qk_l[d];
      for (int o = 32; o > 0; o >>= 1) val += __shfl_xor(val, o);
      if (d == 0){
        float sv = (val + bkq_s) * 0.125f;
        w_l[s] = (mf_l[s] != 0.f) ? sv : -1e30f;
      }
    }
  }
  __syncthreads();

  float mx = blk_max512(red, t, w_l[t]);
  float ex = expf(w_l[t] - mx);
  float Z  = blk_sum512(red, t, ex);
  float wgt = ex / Z;
  __syncthreads();
  w_l[t] = wgt;
  wgt_g[bb*512 + t] = wgt;
  __syncthreads();

  if (t < 300){
    float acc = 0.f;
    #pragma unroll 4
    for (int s = 0; s < 512; ++s) acc += w_l[s] * feat_tab[(size_t)ids_l[s]*300 + t];
    Fbar_g[bb*300 + t] = acc;
  }
  for (int j = t; j < 600; j += 512){
    float acc = 0.f;
    for (int i = 0; i < 300; ++i) acc += sgs_l[i]*ln1g[300 + i]*w1[(300 + i)*600 + j];
    V_g[bb*600 + j] = acc;
  }
}

// ---------------- K2: hbar ----------------
__global__ __launch_bounds__(640)
void k_hbar(const int* __restrict__ ids_a, const int* __restrict__ ids_b,
            const __hip_bfloat16* __restrict__ U, const float* __restrict__ fsum, const float* __restrict__ fsq,
            const float* __restrict__ ssum_g, const float* __restrict__ ssq_g,
            const float* __restrict__ V_g, const float* __restrict__ pgw, const float* __restrict__ pcv,
            const float* __restrict__ bias1, const float* __restrict__ wgt_g,
            float* __restrict__ hbar_g)
{
  int bb = blockIdx.x; int b = bb & 127;
  const int* ids = (bb < 128) ? ids_a : ids_b;
  int t = threadIdx.x;
  __shared__ int id_l[512];
  __shared__ float m_l[512], rs_l[512], wg_l[512];
  float ss = ssum_g[bb], sq = ssq_g[bb];
  if (t < 512){
    int id = ids[b*512 + t];
    id_l[t] = id;
    float m = (fsum[id] + ss) * (1.f/600.f);
    float var = (fsq[id] + sq) * (1.f/600.f) - m*m;
    m_l[t] = m;
    rs_l[t] = 1.f / sqrtf(var + 1e-5f);
    wg_l[t] = wgt_g[bb*512 + t];
  }
  __syncthreads();
  if (t < 600){
    float gwj = 0.f, cj = 0.f;
    for (int k = 0; k < 8; ++k){ gwj += pgw[k*600 + t]; cj += pcv[k*600 + t]; }
    cj += bias1[t];
    float Vj = V_g[bb*600 + t];
    float acc = 0.f;
    #pragma unroll 4
    for (int s = 0; s < 512; ++s){
      float u = __bfloat162float(U[(size_t)id_l[s]*600 + t]);
      float a = (u + Vj - m_l[s]*gwj)*rs_l[s] + cj;
      acc += wg_l[s] * geluf(a);
    }
    hbar_g[bb*600 + t] = acc;
  }
}

// ---------------- K3: final per-row MLPs ----------------
__global__ __launch_bounds__(512)
void k_final(const float* __restrict__ hbar_g, const float* __restrict__ Fbar_g,
             const float* __restrict__ sgs_g,
             const float* __restrict__ w2, const float* __restrict__ b2,
             const float* __restrict__ ln2g, const float* __restrict__ ln2b,
             const float* __restrict__ aw1, const float* __restrict__ ab1,
             const float* __restrict__ aw2, const float* __restrict__ ab2,
             float* __restrict__ final_g)
{
  int bb = blockIdx.x, t = threadIdx.x;
  __shared__ float hb[600], att[300], sg[300], t2[600], g2[600], red[512];
  for (int j = t; j < 600; j += 512) hb[j] = hbar_g[bb*600 + j];
  if (t < 300) sg[t] = sgs_g[bb*300 + t];
  __syncthreads();
  if (t < 300){
    float acc = b2[t] + Fbar_g[bb*300 + t];
    for (int k = 0; k < 600; ++k) acc += hb[k]*w2[k*300 + t];
    att[t] = acc;
  }
  __syncthreads();
  float S1 = blk_sum512(red, t, (t < 300) ? (sg[t] + att[t]) : 0.f);
  float S2 = blk_sum512(red, t, (t < 300) ? (sg[t]*sg[t] + att[t]*att[t]) : 0.f);
  float m = S1*(1.f/600.f);
  float var = S2*(1.f/600.f) - m*m;
  float rs = 1.f / sqrtf(var + 1e-5f);
  for (int i = t; i < 600; i += 512){
    float x = (i < 300) ? sg[i] : att[i - 300];
    t2[i] = (x - m)*rs*ln2g[i] + ln2b[i];
  }
  __syncthreads();
  for (int j = t; j < 600; j += 512){
    float u = ab1[j];
    for (int i = 0; i < 600; ++i) u += t2[i]*aw1[i*600 + j];
    g2[j] = geluf(u);
  }
  __syncthreads();
  if (t < 300){
    float o = sg[t] + ab2[t];
    for (int i = 0; i < 600; ++i) o += g2[i]*aw2[i*300 + t];
    final_g[bb*300 + t] = o;
  }
}

// ---------------- K4: cosine ----------------
__global__ __launch_bounds__(64)
void k_cos(const float* __restrict__ final_g, float* __restrict__ out){
  int b = blockIdx.x; int lane = threadIdx.x;
  const float* A  = final_g + b*300;
  const float* Bv = final_g + (128 + b)*300;
  float dot = 0.f, na = 0.f, nb = 0.f;
  for (int i = lane; i < 300; i += 64){
    float x = A[i], y = Bv[i];
    dot += x*y; na += x*x; nb += y*y;
  }
  for (int o = 32; o > 0; o >>= 1){
    dot += __shfl_xor(dot, o); na += __shfl_xor(na, o); nb += __shfl_xor(nb, o);
  }
  if (lane == 0){
    float den = fmaxf(sqrtf(na), 1e-8f) * fmaxf(sqrtf(nb), 1e-8f);
    out[b] = 5.f * dot / den;
  }
}

extern "C" void kernel_launch(void* const* d_in, const int* in_sizes, int n_in,
                              void* d_out, int out_size, void* d_ws, size_t ws_size,
                              hipStream_t stream) {
  const int* ids_a = (const int*)d_in[0];
  const void* mask_a = d_in[1];
  const int* ids_b = (const int*)d_in[2];
  const void* mask_b = d_in[3];
  const float* mu_tab     = (const float*)d_in[4];
  const float* logvar_tab = (const float*)d_in[5];
  const float* alpha_tab  = (const float*)d_in[6];
  const float* feat_tab   = (const float*)d_in[7];
  const float* log_tau    = (const float*)d_in[8];
  const float* pos_mu     = (const float*)d_in[9];
  const float* pos_alpha  = (const float*)d_in[10];
  const float* ln1g = (const float*)d_in[11];
  const float* ln1b = (const float*)d_in[12];
  const float* w1   = (const float*)d_in[13];
  const float* b1   = (const float*)d_in[14];
  const float* w2   = (const float*)d_in[15];
  const float* b2   = (const float*)d_in[16];
  const float* wq   = (const float*)d_in[17];
  const float* bq   = (const float*)d_in[18];
  const float* wk   = (const float*)d_in[19];
  const float* bk   = (const float*)d_in[20];
  const float* ln2g = (const float*)d_in[21];
  const float* ln2b = (const float*)d_in[22];
  const float* aw1  = (const float*)d_in[23];
  const float* ab1  = (const float*)d_in[24];
  const float* aw2  = (const float*)d_in[25];
  const float* ab2  = (const float*)d_in[26];
  float* out = (float*)d_out;

  char* wsb = (char*)d_ws;
  size_t off = 0;
  auto take = [&](size_t bytes) -> void* {
    void* p = wsb + off;
    off += (bytes + 255) & ~(size_t)255;
    return p;
  };

  const size_t uBytes  = (size_t)30000 * 600 * 2;   // U bf16
  const size_t aBytes  = (size_t)30080 * 320 * 2;   // packed A bf16
  const size_t btBytes = (size_t)640 * 320 * 2;     // packed B^T bf16
  const size_t need = uBytes + aBytes + btBytes + ((size_t)8 << 20);
  if (ws_size < need) return;   // fail loudly (round-2 evidence: ws >= 80 MB)

  __hip_bfloat16* U = (__hip_bfloat16*)take(uBytes);
  ushort* Abf  = (ushort*)take(aBytes);
  ushort* BTbf = (ushort*)take(btBytes);
  float* fsum   = (float*)take(30000*4);
  float* fsq    = (float*)take(30000*4);
  float* pgw    = (float*)take(8*600*4);
  float* pcv    = (float*)take(8*600*4);
  float* sgs_g  = (float*)take(256*300*4);
  float* ssum_g = (float*)take(256*4);
  float* ssq_g  = (float*)take(256*4);
  float* V_g    = (float*)take(256*600*4);
  float* wgt_g  = (float*)take(256*512*4);
  float* Fbar_g = (float*)take(256*300*4);
  float* hbar_g = (float*)take(256*600*4);
  float* final_g= (float*)take(256*300*4);

  k_pack_a<<<(30080*40 + 255)/256, 256, 0, stream>>>(feat_tab, Abf);
  k_pack_b<<<(640*320 + 255)/256, 256, 0, stream>>>(w1, ln1g, BTbf);
  k_feat_stats<<<7500, 256, 0, stream>>>(feat_tab, fsum, fsq);
  k_gw1_part<<<dim3(3, 8), 256, 0, stream>>>(w1, ln1g, ln1b, pgw, pcv);
  k_ugemm_mfma<<<dim3(235, 5), 256, 0, stream>>>(Abf, BTbf, U);
  k_encode_stage1<<<256, 512, 0, stream>>>(ids_a, mask_a, ids_b, mask_b,
                                           mu_tab, logvar_tab, alpha_tab, feat_tab,
                                           log_tau, pos_mu, pos_alpha,
                                           wq, bq, wk, bk, ln1g, w1,
                                           sgs_g, ssum_g, ssq_g, V_g, wgt_g, Fbar_g);
  k_hbar<<<256, 640, 0, stream>>>(ids_a, ids_b, U, fsum, fsq,
                                  ssum_g, ssq_g, V_g, pgw, pcv, b1, wgt_g, hbar_g);
  k_final<<<256, 512, 0, stream>>>(hbar_g, Fbar_g, sgs_g, w2, b2,
                                   ln2g, ln2b, aw1, ab1, aw2, ab2, final_g);
  k_cos<<<128, 64, 0, stream>>>(final_g, out);
}

// Round 4
// 388.129 us; speedup vs baseline: 2.3158x; 1.4820x over previous
//
#include <hip/hip_runtime.h>
#include <hip/hip_bf16.h>
#include <cstdint>
#include <cstddef>

#define DEV __device__ __forceinline__

// problem constants: B=128, S=512, V=30000, DS=64, DF=300, H=600, BB=256

typedef __attribute__((ext_vector_type(8))) short bf16x8;
typedef __attribute__((ext_vector_type(4))) float f32x4;

DEV float geluf(float x){ return 0.5f*x*(1.f + erff(x*0.7071067811865475f)); }

DEV float blk_sum512(float* red, int t, float v){
  red[t] = v; __syncthreads();
  for (int o = 256; o > 0; o >>= 1){ if (t < o) red[t] += red[t+o]; __syncthreads(); }
  float r = red[0]; __syncthreads(); return r;
}
DEV float blk_max512(float* red, int t, float v){
  red[t] = v; __syncthreads();
  for (int o = 256; o > 0; o >>= 1){ if (t < o) red[t] = fmaxf(red[t], red[t+o]); __syncthreads(); }
  float r = red[0]; __syncthreads(); return r;
}

DEV ushort f2bf(float v){ __hip_bfloat16 h = __float2bfloat16(v); return *(ushort*)&h; }
DEV float bf2f(ushort u){ __hip_bfloat16 h; *(ushort*)&h = u; return __bfloat162float(h); }

// ---- mask dtype classifier (bool may arrive as u8 / int32 / bf16) ----
DEV int mask_mode(const unsigned char* m){
  bool big = false, off123 = false, off0one = false;
  #pragma unroll
  for (int i = 0; i < 16; ++i){
    unsigned char c = m[i];
    if (c > 1) big = true;
    if ((i & 3) != 0 && c != 0) off123 = true;
    if ((i & 3) == 0 && c == 1) off0one = true;
  }
  if (big) return 2;
  if (!off123 && off0one) return 1;
  return 0;
}
DEV float mask_read(const void* m, int idx, int mode){
  if (mode == 1) return ((const int*)m)[idx] ? 1.f : 0.f;
  if (mode == 2) return ((const unsigned short*)m)[idx] ? 1.f : 0.f;
  return ((const unsigned char*)m)[idx] ? 1.f : 0.f;
}

// ---------------- P0a: per-vocab feature stats ----------------
__global__ __launch_bounds__(256)
void k_feat_stats(const float* __restrict__ feat, float* __restrict__ fsum, float* __restrict__ fsq){
  int v = blockIdx.x*4 + (threadIdx.x >> 6);
  int lane = threadIdx.x & 63;
  if (v >= 30000) return;
  float s = 0.f, q = 0.f;
  for (int i = lane; i < 300; i += 64){ float f = feat[v*300 + i]; s += f; q += f*f; }
  for (int o = 32; o > 0; o >>= 1){ s += __shfl_xor(s, o); q += __shfl_xor(q, o); }
  if (lane == 0){ fsum[v] = s; fsq[v] = q; }
}

// ---------------- P0b: gw1/cv partials ----------------
__global__ __launch_bounds__(256)
void k_gw1_part(const float* __restrict__ w1, const float* __restrict__ g,
                const float* __restrict__ bln, float* __restrict__ pgw, float* __restrict__ pcv){
  int j = blockIdx.x*256 + threadIdx.x;
  int ic = blockIdx.y;
  if (j >= 600) return;
  float a = 0.f, c = 0.f;
  for (int i = ic*75; i < ic*75 + 75; ++i){
    float w = w1[i*600 + j];
    a += g[i]*w; c += bln[i]*w;
  }
  pgw[ic*600 + j] = a; pcv[ic*600 + j] = c;
}

__global__ __launch_bounds__(256)
void k_gw_reduce(const float* __restrict__ pgw, const float* __restrict__ pcv,
                 const float* __restrict__ b1, float* __restrict__ gw_g, float* __restrict__ c_g){
  int j = blockIdx.x*256 + threadIdx.x;
  if (j >= 600) return;
  float a = 0.f, c = 0.f;
  for (int k = 0; k < 8; ++k){ a += pgw[k*600 + j]; c += pcv[k*600 + j]; }
  gw_g[j] = a; c_g[j] = c + b1[j];
}

// ---------------- pack A: feat -> bf16 [30080][320] (K zero-padded) ----------------
__global__ __launch_bounds__(256)
void k_pack_a(const float* __restrict__ feat, ushort* __restrict__ A){
  int idx = blockIdx.x*256 + threadIdx.x;          // octet index
  if (idx >= 30080*40) return;
  int v = idx / 40, ko = (idx % 40)*8;
  union { ushort u[8]; bf16x8 v8; } pk;
  #pragma unroll
  for (int i = 0; i < 8; ++i){
    int k = ko + i;
    float val = (v < 30000 && k < 300) ? feat[(size_t)v*300 + k] : 0.f;
    pk.u[i] = f2bf(val);
  }
  *(bf16x8*)&A[(size_t)idx*8] = pk.v8;
}

// ---------------- pack B^T: BT[n][k] = g[k]*w1[k*600+n], bf16 [640][320] ----------------
__global__ __launch_bounds__(256)
void k_pack_b(const float* __restrict__ w1, const float* __restrict__ g, ushort* __restrict__ BT){
  int id = blockIdx.x*256 + threadIdx.x;           // 640*320
  if (id >= 640*320) return;
  int n = id % 640, k = id / 640;
  float val = (k < 300 && n < 600) ? g[k]*w1[k*600 + n] : 0.f;
  BT[(size_t)n*320 + k] = f2bf(val);
}

// ---------------- P1: U = A @ B via MFMA 16x16x32 bf16, 128x128 tile ----------------
__global__ __launch_bounds__(256)
void k_ugemm_mfma(const ushort* __restrict__ A, const ushort* __restrict__ BT,
                  __hip_bfloat16* __restrict__ U){
  __shared__ ushort As[128][40];
  __shared__ ushort Bs[128][40];
  int tid = threadIdx.x;
  int bm = blockIdx.x * 128, bn = blockIdx.y * 128;
  int wid = tid >> 6, lane = tid & 63;
  int wr = wid >> 1, wc = wid & 1;
  int lr = lane & 15, lk = lane >> 4;
  f32x4 acc[4][4] = {};
  for (int k0 = 0; k0 < 320; k0 += 32){
    #pragma unroll
    for (int j = 0; j < 2; ++j){
      int idx = tid + 256*j;
      int row = idx >> 2, ko = (idx & 3)*8;
      *(bf16x8*)&As[row][ko] = *(const bf16x8*)&A[(size_t)(bm+row)*320 + k0 + ko];
      *(bf16x8*)&Bs[row][ko] = *(const bf16x8*)&BT[(size_t)(bn+row)*320 + k0 + ko];
    }
    __syncthreads();
    bf16x8 af[4], bfr[4];
    #pragma unroll
    for (int f = 0; f < 4; ++f){
      af[f]  = *(const bf16x8*)&As[wr*64 + f*16 + lr][lk*8];
      bfr[f] = *(const bf16x8*)&Bs[wc*64 + f*16 + lr][lk*8];
    }
    #pragma unroll
    for (int i = 0; i < 4; ++i)
      #pragma unroll
      for (int j = 0; j < 4; ++j)
        acc[i][j] = __builtin_amdgcn_mfma_f32_16x16x32_bf16(af[i], bfr[j], acc[i][j], 0, 0, 0);
    __syncthreads();
  }
  #pragma unroll
  for (int i = 0; i < 4; ++i){
    #pragma unroll
    for (int j = 0; j < 4; ++j){
      #pragma unroll
      for (int r = 0; r < 4; ++r){
        int row = bm + wr*64 + i*16 + lk*4 + r;
        int col = bn + wc*64 + j*16 + lr;
        if (row < 30000 && col < 600)
          U[(size_t)row*600 + col] = __float2bfloat16(acc[i][j][r]);
      }
    }
  }
}

// ---------------- K1: stage 1 (restructured: staged mu, grouped float4 gathers) ----------------
__global__ __launch_bounds__(512)
void k_encode_stage1(const int* __restrict__ ids_a, const void* __restrict__ mask_a,
                     const int* __restrict__ ids_b, const void* __restrict__ mask_b,
                     const float* __restrict__ mu_tab, const float* __restrict__ logvar_tab,
                     const float* __restrict__ alpha_tab, const float* __restrict__ feat_tab,
                     const float* __restrict__ log_tau, const float* __restrict__ pos_mu,
                     const float* __restrict__ pos_alpha,
                     const float* __restrict__ wq, const float* __restrict__ bq,
                     const float* __restrict__ wk, const float* __restrict__ bk,
                     ushort* __restrict__ MuS,
                     float* __restrict__ sgs_g, float* __restrict__ ssum_g, float* __restrict__ ssq_g,
                     float* __restrict__ wgt_g)
{
  int bb = blockIdx.x;
  const int* ids = (bb < 128) ? ids_a : ids_b;
  const void* msk = (bb < 128) ? mask_a : mask_b;
  int b = bb & 127;
  int t = threadIdx.x;

  __shared__ int   ids_l[512];
  __shared__ float mf_l[512], al_l[512], w_l[512], red[512];
  __shared__ float cent[64], q_l[64], qk_l[64];
  __shared__ float sgs_l[304];
  __shared__ float gpart[32][64];   // group centroid partials
  __shared__ float pacc[8][304];    // wave render partials
  __shared__ float bkq_s;
  __shared__ int mmode;

  if (t == 0) mmode = mask_mode((const unsigned char*)msk);
  __syncthreads();

  // phase 0: ids/mask/alpha
  {
    int id = ids[b*512 + t];
    float mf = mask_read(msk, b*512 + t, mmode);
    ids_l[t] = id; mf_l[t] = mf;
    float pa = pos_alpha[t];
    al_l[t] = alpha_tab[id] * (1.f/(1.f + expf(-pa))) * mf;
  }
  __syncthreads();
  float msum = blk_sum512(red, t, mf_l[t]);

  int grp = t >> 4, sub = t & 15;   // 32 groups x 16 lanes
  ushort* MuB = MuS + (size_t)bb*512*64;

  // phase 1: gather mu+pos once (float4), stage bf16, centroid partials (fp32)
  {
    float cp0=0.f, cp1=0.f, cp2=0.f, cp3=0.f;
    for (int k = 0; k < 16; ++k){
      int s = (grp << 4) | k;
      int id = ids_l[s];
      float4 m4 = *(const float4*)&mu_tab[(size_t)id*64 + sub*4];
      float4 p4 = *(const float4*)&pos_mu[s*64 + sub*4];
      float v0 = m4.x + p4.x, v1 = m4.y + p4.y, v2 = m4.z + p4.z, v3 = m4.w + p4.w;
      ushort4 st; st.x = f2bf(v0); st.y = f2bf(v1); st.z = f2bf(v2); st.w = f2bf(v3);
      *(ushort4*)&MuB[(size_t)s*64 + sub*4] = st;
      float mf = mf_l[s];
      cp0 += mf*v0; cp1 += mf*v1; cp2 += mf*v2; cp3 += mf*v3;
    }
    gpart[grp][sub*4+0] = cp0; gpart[grp][sub*4+1] = cp1;
    gpart[grp][sub*4+2] = cp2; gpart[grp][sub*4+3] = cp3;
  }
  __syncthreads();
  if (t < 64){
    float c = 0.f;
    for (int g = 0; g < 32; ++g) c += gpart[g][t];
    cent[t] = c / fmaxf(msum, 1.f);
  }
  __syncthreads();

  // phase 2: d2 -> w = alpha*K  (staged mu + float4 logvar gather)
  {
    float itau = expf(-log_tau[0]);
    float c0 = cent[sub*4+0], c1 = cent[sub*4+1], c2 = cent[sub*4+2], c3 = cent[sub*4+3];
    for (int k = 0; k < 16; ++k){
      int s = (grp << 4) | k;
      int id = ids_l[s];
      float4 lv = *(const float4*)&logvar_tab[(size_t)id*64 + sub*4];
      ushort4 mu = *(const ushort4*)&MuB[(size_t)s*64 + sub*4];
      float d0 = bf2f(mu.x) - c0, d1 = bf2f(mu.y) - c1, d2v = bf2f(mu.z) - c2, d3 = bf2f(mu.w) - c3;
      float val = d0*d0*expf(-lv.x) + d1*d1*expf(-lv.y) + d2v*d2v*expf(-lv.z) + d3*d3*expf(-lv.w);
      val += __shfl_xor(val, 1); val += __shfl_xor(val, 2);
      val += __shfl_xor(val, 4); val += __shfl_xor(val, 8);
      if (sub == 0){
        float K = expf(-0.5f * val * itau) * mf_l[s];
        w_l[s] = al_l[s] * K;
      }
    }
  }
  __syncthreads();
  float wsum = blk_sum512(red, t, w_l[t]);

  // phase 3: sgs render — wave-per-token, float4 feat gathers
  {
    int wv = t >> 6, ln = t & 63;
    float a10=0.f,a11=0.f,a12=0.f,a13=0.f, a20=0.f,a21=0.f,a22=0.f,a23=0.f;
    for (int k = 0; k < 64; ++k){
      int s = (wv << 6) | k;
      float w = w_l[s];
      const float* fr = &feat_tab[(size_t)ids_l[s]*300];
      float4 v1 = *(const float4*)&fr[ln*4];
      a10 += w*v1.x; a11 += w*v1.y; a12 += w*v1.z; a13 += w*v1.w;
      if (ln < 11){
        float4 v2 = *(const float4*)&fr[256 + ln*4];
        a20 += w*v2.x; a21 += w*v2.y; a22 += w*v2.z; a23 += w*v2.w;
      }
    }
    pacc[wv][ln*4+0]=a10; pacc[wv][ln*4+1]=a11; pacc[wv][ln*4+2]=a12; pacc[wv][ln*4+3]=a13;
    if (ln < 11){
      pacc[wv][256+ln*4+0]=a20; pacc[wv][256+ln*4+1]=a21;
      pacc[wv][256+ln*4+2]=a22; pacc[wv][256+ln*4+3]=a23;
    }
  }
  __syncthreads();
  if (t < 300){
    float sacc = 0.f;
    #pragma unroll
    for (int w = 0; w < 8; ++w) sacc += pacc[w][t];
    float sv = sacc / fmaxf(wsum, 1e-8f);
    sgs_l[t] = sv;
    sgs_g[bb*300 + t] = sv;
  }
  __syncthreads();
  float ssum = blk_sum512(red, t, (t < 300) ? sgs_l[t] : 0.f);
  float ssq  = blk_sum512(red, t, (t < 300) ? sgs_l[t]*sgs_l[t] : 0.f);
  if (t == 0){ ssum_g[bb] = ssum; ssq_g[bb] = ssq; }

  // phase 4: query = sgs@wq + bq ; qk = wk@q ; bkq = bk.q
  if (t < 64){
    float q = bq[t];
    for (int i = 0; i < 300; ++i) q += sgs_l[i]*wq[i*64 + t];
    q_l[t] = q;
  }
  __syncthreads();
  if (t < 64){
    float a = 0.f;
    for (int j = 0; j < 64; ++j) a += wk[t*64 + j]*q_l[j];
    qk_l[t] = a;
  }
  if (t == 0){
    float s = 0.f;
    for (int j = 0; j < 64; ++j) s += bk[j]*q_l[j];
    bkq_s = s;
  }
  __syncthreads();

  // phase 5: scores from staged mu (L2-hot)
  {
    float q0 = qk_l[sub*4+0], q1 = qk_l[sub*4+1], q2 = qk_l[sub*4+2], q3 = qk_l[sub*4+3];
    for (int k = 0; k < 16; ++k){
      int s = (grp << 4) | k;
      ushort4 mu = *(const ushort4*)&MuB[(size_t)s*64 + sub*4];
      float val = bf2f(mu.x)*q0 + bf2f(mu.y)*q1 + bf2f(mu.z)*q2 + bf2f(mu.w)*q3;
      val += __shfl_xor(val, 1); val += __shfl_xor(val, 2);
      val += __shfl_xor(val, 4); val += __shfl_xor(val, 8);
      if (sub == 0){
        float sv = (val + bkq_s) * 0.125f;
        w_l[s] = (mf_l[s] != 0.f) ? sv : -1e30f;
      }
    }
  }
  __syncthreads();

  // phase 6: softmax
  float mx = blk_max512(red, t, w_l[t]);
  float ex = expf(w_l[t] - mx);
  float Z  = blk_sum512(red, t, ex);
  wgt_g[bb*512 + t] = ex / Z;
}

// ---------------- k_vgemm: V[bb][j] = sum_i sgs[bb][i]*g[300+i]*w1[(300+i)*600+j] ----------------
__global__ __launch_bounds__(256)
void k_vgemm(const float* __restrict__ sgs_g, const float* __restrict__ w1,
             const float* __restrict__ ln1g, float* __restrict__ V_g){
  int j = blockIdx.x;        // 600
  int bb = threadIdx.x;      // 256
  __shared__ float col[300];
  for (int i = threadIdx.x; i < 300; i += 256)
    col[i] = ln1g[300 + i]*w1[(size_t)(300 + i)*600 + j];
  __syncthreads();
  const float* sr = &sgs_g[bb*300];
  float acc = 0.f;
  #pragma unroll 4
  for (int i = 0; i < 300; ++i) acc += sr[i]*col[i];
  V_g[bb*600 + j] = acc;
}

// ---------------- K2: merged hbar + Fbar — wave-per-token gathers ----------------
__global__ __launch_bounds__(512)
void k_hbar_fbar(const int* __restrict__ ids_a, const int* __restrict__ ids_b,
                 const __hip_bfloat16* __restrict__ U, const float* __restrict__ feat_tab,
                 const float* __restrict__ fsum, const float* __restrict__ fsq,
                 const float* __restrict__ ssum_g, const float* __restrict__ ssq_g,
                 const float* __restrict__ V_g, const float* __restrict__ gw_g,
                 const float* __restrict__ c_g, const float* __restrict__ wgt_g,
                 float* __restrict__ hbar_g, float* __restrict__ Fbar_g)
{
  int bb = blockIdx.x; int b = bb & 127;
  const int* ids = (bb < 128) ? ids_a : ids_b;
  int t = threadIdx.x;
  __shared__ int id_l[512];
  __shared__ float m_l[512], rs_l[512], wg_l[512];
  __shared__ float hp[8][600];
  __shared__ float fp[8][304];
  float ss = ssum_g[bb], sq = ssq_g[bb];
  {
    int id = ids[b*512 + t];
    id_l[t] = id;
    float m = (fsum[id] + ss) * (1.f/600.f);
    float var = (fsq[id] + sq) * (1.f/600.f) - m*m;
    m_l[t] = m;
    rs_l[t] = 1.f / sqrtf(var + 1e-5f);
    wg_l[t] = wgt_g[bb*512 + t];
  }
  __syncthreads();

  int wv = t >> 6, ln = t & 63;
  // per-lane dim constants: primary chunk = dims ln*8..+7 ; secondary (ln<11) = 512+ln*8..+7
  float Vp[8], gwp[8], cp[8], Vs[8], gws[8], cs[8];
  #pragma unroll
  for (int r = 0; r < 8; ++r){
    int j = ln*8 + r;
    Vp[r] = V_g[bb*600 + j]; gwp[r] = gw_g[j]; cp[r] = c_g[j];
    Vs[r] = 0.f; gws[r] = 0.f; cs[r] = 0.f;
  }
  if (ln < 11){
    #pragma unroll
    for (int r = 0; r < 8; ++r){
      int j = 512 + ln*8 + r;
      Vs[r] = V_g[bb*600 + j]; gws[r] = gw_g[j]; cs[r] = c_g[j];
    }
  }
  float h1[8] = {}, h2[8] = {};
  float f10=0.f,f11=0.f,f12=0.f,f13=0.f, f20=0.f,f21=0.f,f22=0.f,f23=0.f;

  for (int k = 0; k < 64; ++k){
    int s = (wv << 6) | k;
    int id = id_l[s];
    float w = wg_l[s], m = m_l[s], rs = rs_l[s];
    const __hip_bfloat16* ur = &U[(size_t)id*600];
    const float* fr = &feat_tab[(size_t)id*300];
    bf16x8 u8 = *(const bf16x8*)&ur[ln*8];
    float4 fv = *(const float4*)&fr[ln*4];
    #pragma unroll
    for (int r = 0; r < 8; ++r){
      float u = bf2f(((ushort)u8[r]));
      float a = (u + Vp[r] - m*gwp[r])*rs + cp[r];
      h1[r] += w*geluf(a);
    }
    f10 += w*fv.x; f11 += w*fv.y; f12 += w*fv.z; f13 += w*fv.w;
    if (ln < 11){
      bf16x8 u8b = *(const bf16x8*)&ur[512 + ln*8];
      float4 fvb = *(const float4*)&fr[256 + ln*4];
      #pragma unroll
      for (int r = 0; r < 8; ++r){
        float u = bf2f(((ushort)u8b[r]));
        float a = (u + Vs[r] - m*gws[r])*rs + cs[r];
        h2[r] += w*geluf(a);
      }
      f20 += w*fvb.x; f21 += w*fvb.y; f22 += w*fvb.z; f23 += w*fvb.w;
    }
  }
  #pragma unroll
  for (int r = 0; r < 8; ++r) hp[wv][ln*8 + r] = h1[r];
  if (ln < 11){
    #pragma unroll
    for (int r = 0; r < 8; ++r) hp[wv][512 + ln*8 + r] = h2[r];
  }
  fp[wv][ln*4+0]=f10; fp[wv][ln*4+1]=f11; fp[wv][ln*4+2]=f12; fp[wv][ln*4+3]=f13;
  if (ln < 11){
    fp[wv][256+ln*4+0]=f20; fp[wv][256+ln*4+1]=f21;
    fp[wv][256+ln*4+2]=f22; fp[wv][256+ln*4+3]=f23;
  }
  __syncthreads();
  for (int j = t; j < 600; j += 512){
    float s = 0.f;
    #pragma unroll
    for (int w = 0; w < 8; ++w) s += hp[w][j];
    hbar_g[bb*600 + j] = s;
  }
  if (t < 300){
    float s = 0.f;
    #pragma unroll
    for (int w = 0; w < 8; ++w) s += fp[w][t];
    Fbar_g[bb*300 + t] = s;
  }
}

// ---------------- K3: final per-row MLPs ----------------
__global__ __launch_bounds__(512)
void k_final(const float* __restrict__ hbar_g, const float* __restrict__ Fbar_g,
             const float* __restrict__ sgs_g,
             const float* __restrict__ w2, const float* __restrict__ b2,
             const float* __restrict__ ln2g, const float* __restrict__ ln2b,
             const float* __restrict__ aw1, const float* __restrict__ ab1,
             const float* __restrict__ aw2, const float* __restrict__ ab2,
             float* __restrict__ final_g)
{
  int bb = blockIdx.x, t = threadIdx.x;
  __shared__ float hb[600], att[300], sg[300], t2[600], g2[600], red[512];
  for (int j = t; j < 600; j += 512) hb[j] = hbar_g[bb*600 + j];
  if (t < 300) sg[t] = sgs_g[bb*300 + t];
  __syncthreads();
  if (t < 300){
    float acc = b2[t] + Fbar_g[bb*300 + t];
    for (int k = 0; k < 600; ++k) acc += hb[k]*w2[k*300 + t];
    att[t] = acc;
  }
  __syncthreads();
  float S1 = blk_sum512(red, t, (t < 300) ? (sg[t] + att[t]) : 0.f);
  float S2 = blk_sum512(red, t, (t < 300) ? (sg[t]*sg[t] + att[t]*att[t]) : 0.f);
  float m = S1*(1.f/600.f);
  float var = S2*(1.f/600.f) - m*m;
  float rs = 1.f / sqrtf(var + 1e-5f);
  for (int i = t; i < 600; i += 512){
    float x = (i < 300) ? sg[i] : att[i - 300];
    t2[i] = (x - m)*rs*ln2g[i] + ln2b[i];
  }
  __syncthreads();
  for (int j = t; j < 600; j += 512){
    float u = ab1[j];
    for (int i = 0; i < 600; ++i) u += t2[i]*aw1[i*600 + j];
    g2[j] = geluf(u);
  }
  __syncthreads();
  if (t < 300){
    float o = sg[t] + ab2[t];
    for (int i = 0; i < 600; ++i) o += g2[i]*aw2[i*300 + t];
    final_g[bb*300 + t] = o;
  }
}

// ---------------- K4: cosine ----------------
__global__ __launch_bounds__(64)
void k_cos(const float* __restrict__ final_g, float* __restrict__ out){
  int b = blockIdx.x; int lane = threadIdx.x;
  const float* A  = final_g + b*300;
  const float* Bv = final_g + (128 + b)*300;
  float dot = 0.f, na = 0.f, nb = 0.f;
  for (int i = lane; i < 300; i += 64){
    float x = A[i], y = Bv[i];
    dot += x*y; na += x*x; nb += y*y;
  }
  for (int o = 32; o > 0; o >>= 1){
    dot += __shfl_xor(dot, o); na += __shfl_xor(na, o); nb += __shfl_xor(nb, o);
  }
  if (lane == 0){
    float den = fmaxf(sqrtf(na), 1e-8f) * fmaxf(sqrtf(nb), 1e-8f);
    out[b] = 5.f * dot / den;
  }
}

extern "C" void kernel_launch(void* const* d_in, const int* in_sizes, int n_in,
                              void* d_out, int out_size, void* d_ws, size_t ws_size,
                              hipStream_t stream) {
  const int* ids_a = (const int*)d_in[0];
  const void* mask_a = d_in[1];
  const int* ids_b = (const int*)d_in[2];
  const void* mask_b = d_in[3];
  const float* mu_tab     = (const float*)d_in[4];
  const float* logvar_tab = (const float*)d_in[5];
  const float* alpha_tab  = (const float*)d_in[6];
  const float* feat_tab   = (const float*)d_in[7];
  const float* log_tau    = (const float*)d_in[8];
  const float* pos_mu     = (const float*)d_in[9];
  const float* pos_alpha  = (const float*)d_in[10];
  const float* ln1g = (const float*)d_in[11];
  const float* ln1b = (const float*)d_in[12];
  const float* w1   = (const float*)d_in[13];
  const float* b1   = (const float*)d_in[14];
  const float* w2   = (const float*)d_in[15];
  const float* b2   = (const float*)d_in[16];
  const float* wq   = (const float*)d_in[17];
  const float* bq   = (const float*)d_in[18];
  const float* wk   = (const float*)d_in[19];
  const float* bk   = (const float*)d_in[20];
  const float* ln2g = (const float*)d_in[21];
  const float* ln2b = (const float*)d_in[22];
  const float* aw1  = (const float*)d_in[23];
  const float* ab1  = (const float*)d_in[24];
  const float* aw2  = (const float*)d_in[25];
  const float* ab2  = (const float*)d_in[26];
  float* out = (float*)d_out;

  char* wsb = (char*)d_ws;
  size_t off = 0;
  auto take = [&](size_t bytes) -> void* {
    void* p = wsb + off;
    off += (bytes + 255) & ~(size_t)255;
    return p;
  };

  const size_t uBytes  = (size_t)30000 * 600 * 2;   // U bf16          36.0 MB
  const size_t aBytes  = (size_t)30080 * 320 * 2;   // packed A bf16   19.3 MB
  const size_t btBytes = (size_t)640 * 320 * 2;     // packed B^T      0.41 MB
  const size_t muBytes = (size_t)256 * 512 * 64 * 2;// staged mu bf16  16.8 MB
  const size_t need = uBytes + aBytes + btBytes + muBytes + ((size_t)4 << 20);
  if (ws_size < need) return;   // ws >= 80MB proven in round 2

  __hip_bfloat16* U = (__hip_bfloat16*)take(uBytes);
  ushort* Abf  = (ushort*)take(aBytes);
  ushort* BTbf = (ushort*)take(btBytes);
  ushort* MuS  = (ushort*)take(muBytes);
  float* fsum   = (float*)take(30000*4);
  float* fsq    = (float*)take(30000*4);
  float* pgw    = (float*)take(8*600*4);
  float* pcv    = (float*)take(8*600*4);
  float* gw_g   = (float*)take(600*4);
  float* c_g    = (float*)take(600*4);
  float* sgs_g  = (float*)take(256*300*4);
  float* ssum_g = (float*)take(256*4);
  float* ssq_g  = (float*)take(256*4);
  float* V_g    = (float*)take(256*600*4);
  float* wgt_g  = (float*)take(256*512*4);
  float* Fbar_g = (float*)take(256*300*4);
  float* hbar_g = (float*)take(256*600*4);
  float* final_g= (float*)take(256*300*4);

  k_pack_a<<<(30080*40 + 255)/256, 256, 0, stream>>>(feat_tab, Abf);
  k_pack_b<<<(640*320 + 255)/256, 256, 0, stream>>>(w1, ln1g, BTbf);
  k_feat_stats<<<7500, 256, 0, stream>>>(feat_tab, fsum, fsq);
  k_gw1_part<<<dim3(3, 8), 256, 0, stream>>>(w1, ln1g, ln1b, pgw, pcv);
  k_gw_reduce<<<3, 256, 0, stream>>>(pgw, pcv, b1, gw_g, c_g);
  k_ugemm_mfma<<<dim3(235, 5), 256, 0, stream>>>(Abf, BTbf, U);
  k_encode_stage1<<<256, 512, 0, stream>>>(ids_a, mask_a, ids_b, mask_b,
                                           mu_tab, logvar_tab, alpha_tab, feat_tab,
                                           log_tau, pos_mu, pos_alpha,
                                           wq, bq, wk, bk,
                                           MuS, sgs_g, ssum_g, ssq_g, wgt_g);
  k_vgemm<<<600, 256, 0, stream>>>(sgs_g, w1, ln1g, V_g);
  k_hbar_fbar<<<256, 512, 0, stream>>>(ids_a, ids_b, U, feat_tab, fsum, fsq,
                                       ssum_g, ssq_g, V_g, gw_g, c_g, wgt_g,
                                       hbar_g, Fbar_g);
  k_final<<<256, 512, 0, stream>>>(hbar_g, Fbar_g, sgs_g, w2, b2,
                                   ln2g, ln2b, aw1, ab1, aw2, ab2, final_g);
  k_cos<<<128, 64, 0, stream>>>(final_g, out);
}